// Round 2
// baseline (206283.252 us; speedup 1.0000x reference)
//
#include <hip/hip_runtime.h>
#include <math.h>

// Persistent weight-stationary seq2seq GRU + exact JAX threefry sampling.
// R2: single persistent kernel (256 WGs = 1/CU), weights in LDS, tree
// grid-barrier between recurrence steps. All dot products keep R1's exact
// fmaf ordering -> sampled tokens bit-identical to the validated R1 run.

#define BB 64
#define TT 512
#define VV 390
#define EE 256
#define HH 512
#define NTHR 256

static __device__ __forceinline__ void tf2x32(unsigned k0, unsigned k1,
                                              unsigned x0, unsigned x1,
                                              unsigned &o0, unsigned &o1) {
  unsigned ks2 = k0 ^ k1 ^ 0x1BD11BDAu;
  x0 += k0; x1 += k1;
#define TFR(r) x0 += x1; x1 = (x1 << (r)) | (x1 >> (32 - (r))); x1 ^= x0;
  TFR(13) TFR(15) TFR(26) TFR(6)
  x0 += k1; x1 += ks2 + 1u;
  TFR(17) TFR(29) TFR(16) TFR(24)
  x0 += ks2; x1 += k0 + 2u;
  TFR(13) TFR(15) TFR(26) TFR(6)
  x0 += k0; x1 += k1 + 3u;
  TFR(17) TFR(29) TFR(16) TFR(24)
  x0 += k1; x1 += ks2 + 4u;
  TFR(13) TFR(15) TFR(26) TFR(6)
  x0 += ks2; x1 += k0 + 5u;
#undef TFR
  o0 = x0; o1 = x1;
}

static __device__ __forceinline__ float sigm(float x) {
  return 1.0f / (1.0f + expf(-x));
}

// 3 dot products of rows w0/w1/w2 (contiguous, len K) against X laid out
// [k][64]. EXACT R1 fmaf ordering — do not touch (token bit-exactness).
template <int K>
static __device__ __forceinline__ void dot3_kb(const float* __restrict__ X, int b,
    const float* __restrict__ w0, const float* __restrict__ w1,
    const float* __restrict__ w2, float &r0, float &r1, float &r2) {
  const float4* q0 = (const float4*)w0;
  const float4* q1 = (const float4*)w1;
  const float4* q2 = (const float4*)w2;
  float s0 = 0.f, s1 = 0.f, s2 = 0.f;
#pragma unroll 4
  for (int k4 = 0; k4 < (K >> 2); ++k4) {
    float4 u0 = q0[k4], u1 = q1[k4], u2 = q2[k4];
    int kb = (k4 << 8) + b;
    float x0 = X[kb], x1 = X[kb + 64], x2 = X[kb + 128], x3 = X[kb + 192];
    s0 = fmaf(x0, u0.x, s0); s0 = fmaf(x1, u0.y, s0); s0 = fmaf(x2, u0.z, s0); s0 = fmaf(x3, u0.w, s0);
    s1 = fmaf(x0, u1.x, s1); s1 = fmaf(x1, u1.y, s1); s1 = fmaf(x2, u1.z, s1); s1 = fmaf(x3, u1.w, s1);
    s2 = fmaf(x0, u2.x, s2); s2 = fmaf(x1, u2.y, s2); s2 = fmaf(x2, u2.z, s2); s2 = fmaf(x3, u2.w, s2);
  }
  r0 = s0; r1 = s1; r2 = s2;
}

// Tree grid barrier: 16 groups x 16 WGs, monotone generation counters.
// bar[0]=root, bar[32+g*32]=group counters (128B apart).
static __device__ __forceinline__ void gbar(unsigned* bar, unsigned gen, int wg) {
  __syncthreads();
  if (threadIdx.x == 0) {
    unsigned tgt = gen * 16u;
    unsigned* grp = bar + 32 + (wg >> 4) * 32;
    __hip_atomic_fetch_add(grp, 1u, __ATOMIC_RELEASE, __HIP_MEMORY_SCOPE_AGENT);
    if ((wg & 15) == 0) {
      while (__hip_atomic_load(grp, __ATOMIC_ACQUIRE, __HIP_MEMORY_SCOPE_AGENT) < tgt)
        __builtin_amdgcn_s_sleep(1);
      __hip_atomic_fetch_add(bar, 1u, __ATOMIC_RELEASE, __HIP_MEMORY_SCOPE_AGENT);
    }
    while (__hip_atomic_load(bar, __ATOMIC_ACQUIRE, __HIP_MEMORY_SCOPE_AGENT) < tgt)
      __builtin_amdgcn_s_sleep(1);
  }
  __syncthreads();
}

__global__ __launch_bounds__(256) void k_init(float* __restrict__ out,
    float* __restrict__ h1buf, float* __restrict__ h2buf,
    float* __restrict__ xeT, unsigned* __restrict__ rng,
    unsigned* __restrict__ bar, const float* __restrict__ demb) {
  int wg = blockIdx.x, tid = threadIdx.x;
  for (int i = wg * 256 + tid; i < HH * BB; i += 64 * 256) {
    h1buf[i] = 0.f;  // slot 0 only (slot 1 written before first read)
    h2buf[i] = 0.f;
  }
  for (int v = tid; v < VV; v += 256)
    out[(size_t)wg * TT * VV + v] = (v == 388) ? 1.0f : 0.0f;
  xeT[tid * 64 + wg] = demb[388 * EE + tid];  // xe for step 0 (token 388)
  if (tid == 0) {
    out[(size_t)BB * TT * VV + (size_t)wg * TT] = 388.0f;
    if (wg == 0) { rng[0] = 0u; rng[1] = 42u; rng[2] = 0u; rng[3] = 0u; }
  }
  if (wg == 0)
    for (int i = tid; i < 544; i += 256) bar[i] = 0u;
}

// x[t][e][b] = sum_v input[b][t][v] * emb[v][e]; one WG per t. (R1 verbatim)
__global__ __launch_bounds__(256) void k_xgemm(const float* __restrict__ input,
    const float* __restrict__ emb, float* __restrict__ xT) {
  int t = blockIdx.x, tid = threadIdx.x;
  int s = tid >> 6, b = tid & 63;
  __shared__ float lin[64 * 65];
  float4 acc[16];
#pragma unroll
  for (int i = 0; i < 16; ++i) acc[i] = make_float4(0.f, 0.f, 0.f, 0.f);
  for (int k0 = 0; k0 < VV; k0 += 64) {
    int kmax = min(64, VV - k0);
    __syncthreads();
#pragma unroll
    for (int r = 0; r < 16; ++r) {
      int idx = r * 256 + tid;
      int b2 = idx >> 6, kk = idx & 63;
      if (kk < kmax)
        lin[kk * 65 + b2] = input[((size_t)b2 * TT + t) * VV + k0 + kk];
    }
    __syncthreads();
    for (int kk = 0; kk < kmax; ++kk) {
      float xv = lin[kk * 65 + b];
      const float4* er = (const float4*)(emb + (size_t)(k0 + kk) * EE);
#pragma unroll
      for (int i = 0; i < 16; ++i) {
        float4 w = er[s + 4 * i];
        acc[i].x = fmaf(xv, w.x, acc[i].x);
        acc[i].y = fmaf(xv, w.y, acc[i].y);
        acc[i].z = fmaf(xv, w.z, acc[i].z);
        acc[i].w = fmaf(xv, w.w, acc[i].w);
      }
    }
  }
  float* dst0 = xT + (size_t)t * (EE * 64);
#pragma unroll
  for (int i = 0; i < 16; ++i) {
    int e = (s + 4 * i) * 4;
    float* d = dst0 + e * 64 + b;
    d[0] = acc[i].x; d[64] = acc[i].y; d[128] = acc[i].z; d[192] = acc[i].w;
  }
}

// LDS layout (floats):
//     0 encL0 u0 (3x768)   2304 encL0 u1   4608 encL1 u0 (3x1024)  7680 encL1 u1
// 10752 decL0 u0 (3x768)  13056 decL0 u1  15360 decL1 u0 (3x1024) 18432 decL1 u1
// 21504 scratch (1536): GRU partials / D5 head scratch
__global__ __launch_bounds__(256) void k_seq(
    const float* __restrict__ xT, float* __restrict__ h1buf, float* __restrict__ h2buf,
    float* __restrict__ xeT, unsigned* __restrict__ rng, unsigned* __restrict__ bar,
    const float* __restrict__ eWih0, const float* __restrict__ eWhh0,
    const float* __restrict__ ebih0, const float* __restrict__ ebhh0,
    const float* __restrict__ eWih1, const float* __restrict__ eWhh1,
    const float* __restrict__ ebih1, const float* __restrict__ ebhh1,
    const float* __restrict__ demb,
    const float* __restrict__ dWih0, const float* __restrict__ dWhh0,
    const float* __restrict__ dbih0, const float* __restrict__ dbhh0,
    const float* __restrict__ dWih1, const float* __restrict__ dWhh1,
    const float* __restrict__ dbih1, const float* __restrict__ dbhh1,
    const float* __restrict__ Wp1, const float* __restrict__ bp1,
    const float* __restrict__ Wp2, const float* __restrict__ bp2,
    float* __restrict__ out) {
  extern __shared__ float smem[];
  int wg = blockIdx.x, tid = threadIdx.x;
  int wv = tid >> 6, b = tid & 63;
  float* scr = smem + 21504;

  // ---- stage this WG's weight slices into LDS (j = 2*wg, 2*wg+1) ----
  for (int u = 0; u < 2; ++u) {
    int j = 2 * wg + u;
    for (int g = 0; g < 3; ++g) {
      float* d0 = smem + u * 2304 + g * 768;          // enc L0: [Wih(256)|Whh(512)]
      const float* s0 = eWih0 + (size_t)(g * 512 + j) * EE;
      for (int i = tid; i < EE; i += NTHR) d0[i] = s0[i];
      const float* s1 = eWhh0 + (size_t)(g * 512 + j) * HH;
      for (int i = tid; i < HH; i += NTHR) d0[EE + i] = s1[i];
      float* d1 = smem + 4608 + u * 3072 + g * 1024;  // enc L1: [Wih(512)|Whh(512)]
      const float* s2 = eWih1 + (size_t)(g * 512 + j) * HH;
      for (int i = tid; i < HH; i += NTHR) d1[i] = s2[i];
      const float* s3 = eWhh1 + (size_t)(g * 512 + j) * HH;
      for (int i = tid; i < HH; i += NTHR) d1[HH + i] = s3[i];
      float* d2 = smem + 10752 + u * 2304 + g * 768;  // dec L0
      const float* s4 = dWih0 + (size_t)(g * 512 + j) * EE;
      for (int i = tid; i < EE; i += NTHR) d2[i] = s4[i];
      const float* s5 = dWhh0 + (size_t)(g * 512 + j) * HH;
      for (int i = tid; i < HH; i += NTHR) d2[EE + i] = s5[i];
      float* d3 = smem + 15360 + u * 3072 + g * 1024; // dec L1
      const float* s6 = dWih1 + (size_t)(g * 512 + j) * HH;
      for (int i = tid; i < HH; i += NTHR) d3[i] = s6[i];
      const float* s7 = dWhh1 + (size_t)(g * 512 + j) * HH;
      for (int i = tid; i < HH; i += NTHR) d3[HH + i] = s7[i];
    }
  }
  __syncthreads();
  unsigned gen = 0;

  // ---- encoder: pipelined L0(step t) + L1(step t-1), 1 barrier/iter ----
  for (int t = 0; t <= TT; ++t) {
    bool isL1 = (wv >= 2);
    bool act = isL1 ? (t >= 1) : (t < TT);
    if (act) {
      int j = 2 * wg + (wv & 1);
      const float* h1r = h1buf + (t & 1) * (HH * BB);
      if (!isL1) {
        const float* wb = smem + (wv & 1) * 2304;
        float ax0, ax1, ax2, ah0, ah1, ah2;
        dot3_kb<EE>(xT + (size_t)t * (EE * 64), b, wb, wb + 768, wb + 1536, ax0, ax1, ax2);
        dot3_kb<HH>(h1r, b, wb + EE, wb + 768 + EE, wb + 1536 + EE, ah0, ah1, ah2);
        float r = sigm((ax0 + ebih0[j]) + (ah0 + ebhh0[j]));
        float z = sigm((ax1 + ebih0[512 + j]) + (ah1 + ebhh0[512 + j]));
        float n = tanhf((ax2 + ebih0[1024 + j]) + r * (ah2 + ebhh0[1024 + j]));
        float* h1w = h1buf + ((t + 1) & 1) * (HH * BB);
        h1w[j * 64 + b] = (1.0f - z) * n + z * h1r[j * 64 + b];
      } else {
        const float* wb = smem + 4608 + (wv & 1) * 3072;
        const float* h2r = h2buf + ((t + 1) & 1) * (HH * BB);
        float ax0, ax1, ax2, ah0, ah1, ah2;
        dot3_kb<HH>(h1r, b, wb, wb + 1024, wb + 2048, ax0, ax1, ax2);
        dot3_kb<HH>(h2r, b, wb + HH, wb + 1024 + HH, wb + 2048 + HH, ah0, ah1, ah2);
        float r = sigm((ax0 + ebih1[j]) + (ah0 + ebhh1[j]));
        float z = sigm((ax1 + ebih1[512 + j]) + (ah1 + ebhh1[512 + j]));
        float n = tanhf((ax2 + ebih1[1024 + j]) + r * (ah2 + ebhh1[1024 + j]));
        float* h2w = h2buf + (t & 1) * (HH * BB);
        h2w[j * 64 + b] = (1.0f - z) * n + z * h2r[j * 64 + b];
      }
    }
    gbar(bar, ++gen, wg);
  }

  // ---- decoder: 511 steps x (L0, L1, head+sample), 3 barriers/step ----
  for (int d = 0; d < TT - 1; ++d) {
    const float* h1r = h1buf + (d & 1) * (HH * BB);
    float* h1w = h1buf + ((d + 1) & 1) * (HH * BB);
    const float* h2r = h2buf + (d & 1) * (HH * BB);
    float* h2w = h2buf + ((d + 1) & 1) * (HH * BB);

    { // D1: dec layer0. wave = (unit, x/h-part); partials -> LDS -> combine.
      int unit = wv & 1, part = wv >> 1;
      const float* wb = smem + 10752 + unit * 2304;
      float a0, a1, a2;
      if (part == 0) dot3_kb<EE>(xeT, b, wb, wb + 768, wb + 1536, a0, a1, a2);
      else           dot3_kb<HH>(h1r, b, wb + EE, wb + 768 + EE, wb + 1536 + EE, a0, a1, a2);
      int pb = ((unit * 2 + part) * 3) * 64 + b;
      scr[pb] = a0; scr[pb + 64] = a1; scr[pb + 128] = a2;
      __syncthreads();
      if (tid < 128) {
        int u2 = tid >> 6, b2 = tid & 63, j2 = 2 * wg + u2;
        float ax0 = scr[(u2 * 6 + 0) * 64 + b2], ax1 = scr[(u2 * 6 + 1) * 64 + b2], ax2 = scr[(u2 * 6 + 2) * 64 + b2];
        float ah0 = scr[(u2 * 6 + 3) * 64 + b2], ah1 = scr[(u2 * 6 + 4) * 64 + b2], ah2 = scr[(u2 * 6 + 5) * 64 + b2];
        float r = sigm((ax0 + dbih0[j2]) + (ah0 + dbhh0[j2]));
        float z = sigm((ax1 + dbih0[512 + j2]) + (ah1 + dbhh0[512 + j2]));
        float n = tanhf((ax2 + dbih0[1024 + j2]) + r * (ah2 + dbhh0[1024 + j2]));
        h1w[j2 * 64 + b2] = (1.0f - z) * n + z * h1r[j2 * 64 + b2];
      }
    }
    gbar(bar, ++gen, wg);

    { // D2: dec layer1 (x-input = fresh h1).
      int unit = wv & 1, part = wv >> 1;
      const float* wb = smem + 15360 + unit * 3072;
      float a0, a1, a2;
      if (part == 0) dot3_kb<HH>(h1w, b, wb, wb + 1024, wb + 2048, a0, a1, a2);
      else           dot3_kb<HH>(h2r, b, wb + HH, wb + 1024 + HH, wb + 2048 + HH, a0, a1, a2);
      int pb = ((unit * 2 + part) * 3) * 64 + b;
      scr[pb] = a0; scr[pb + 64] = a1; scr[pb + 128] = a2;
      __syncthreads();
      if (tid < 128) {
        int u2 = tid >> 6, b2 = tid & 63, j2 = 2 * wg + u2;
        float ax0 = scr[(u2 * 6 + 0) * 64 + b2], ax1 = scr[(u2 * 6 + 1) * 64 + b2], ax2 = scr[(u2 * 6 + 2) * 64 + b2];
        float ah0 = scr[(u2 * 6 + 3) * 64 + b2], ah1 = scr[(u2 * 6 + 4) * 64 + b2], ah2 = scr[(u2 * 6 + 5) * 64 + b2];
        float r = sigm((ax0 + dbih1[j2]) + (ah0 + dbhh1[j2]));
        float z = sigm((ax1 + dbih1[512 + j2]) + (ah1 + dbhh1[512 + j2]));
        float n = tanhf((ax2 + dbih1[1024 + j2]) + r * (ah2 + dbhh1[1024 + j2]));
        h2w[j2 * 64 + b2] = (1.0f - z) * n + z * h2r[j2 * 64 + b2];
      }
    }
    gbar(bar, ++gen, wg);

    if (wg < 64) {  // D5: head + softmax + threefry-gumbel sample (R1 decC).
      float* lh = scr; float* lhid = scr + 512; float* lv = scr + 1024;
      float* rf = scr + 1414; int* ri = (int*)(scr + 1422); int* tokp = (int*)(scr + 1430);
      int brow = wg;
      lh[tid] = h2w[tid * 64 + brow];
      lh[tid + 256] = h2w[(tid + 256) * 64 + brow];
      __syncthreads();
      for (int c = tid; c < HH; c += 256) {
        const float4* w = (const float4*)(Wp1 + (size_t)c * HH);
        float a = 0.f;
#pragma unroll 4
        for (int k4 = 0; k4 < HH / 4; ++k4) {
          float4 q = w[k4];
          float4 hv = *(const float4*)&lh[k4 * 4];
          a = fmaf(hv.x, q.x, a); a = fmaf(hv.y, q.y, a);
          a = fmaf(hv.z, q.z, a); a = fmaf(hv.w, q.w, a);
        }
        a += bp1[c];
        lhid[c] = (a >= 0.f) ? a : 0.1f * a;
      }
      __syncthreads();
      for (int c = tid; c < VV; c += 256) {
        const float4* w = (const float4*)(Wp2 + (size_t)c * HH);
        float a = 0.f;
#pragma unroll 4
        for (int k4 = 0; k4 < HH / 4; ++k4) {
          float4 q = w[k4];
          float4 hv = *(const float4*)&lhid[k4 * 4];
          a = fmaf(hv.x, q.x, a); a = fmaf(hv.y, q.y, a);
          a = fmaf(hv.z, q.z, a); a = fmaf(hv.w, q.w, a);
        }
        lv[c] = a + bp2[c];
      }
      __syncthreads();
      float m = -INFINITY;
      for (int c = tid; c < VV; c += 256) m = fmaxf(m, lv[c]);
      for (int off = 32; off > 0; off >>= 1) m = fmaxf(m, __shfl_down(m, off, 64));
      if ((tid & 63) == 0) rf[tid >> 6] = m;
      __syncthreads();
      if (tid == 0) rf[4] = fmaxf(fmaxf(rf[0], rf[1]), fmaxf(rf[2], rf[3]));
      __syncthreads();
      m = rf[4];
      unsigned k0r = rng[(d & 1) * 2], k1r = rng[(d & 1) * 2 + 1];
      unsigned sk0, sk1;
      tf2x32(k0r, k1r, 0u, 1u, sk0, sk1);
      float by = -INFINITY; int bc = 0x7fffffff;
      for (int c = tid; c < VV; c += 256) {
        unsigned o0, o1;
        tf2x32(sk0, sk1, 0u, (unsigned)(brow * VV + c), o0, o1);
        unsigned bits = o0 ^ o1;
        float f = __uint_as_float(0x3f800000u | (bits >> 9)) - 1.0f;
        float u = (f > 0.f) ? f : 1.17549435e-38f;
        float g = (float)(-log(-log((double)u)));
        float y = lv[c] + g;
        if (y > by || (y == by && c < bc)) { by = y; bc = c; }
      }
      for (int off = 32; off > 0; off >>= 1) {
        float oy = __shfl_down(by, off, 64);
        int oc = __shfl_down(bc, off, 64);
        if (oy > by || (oy == by && oc < bc)) { by = oy; bc = oc; }
      }
      if ((tid & 63) == 0) { rf[tid >> 6] = by; ri[tid >> 6] = bc; }
      __syncthreads();
      if (tid == 0) {
        by = rf[0]; bc = ri[0];
        for (int w2 = 1; w2 < 4; ++w2)
          if (rf[w2] > by || (rf[w2] == by && ri[w2] < bc)) { by = rf[w2]; bc = ri[w2]; }
        *tokp = bc;
        out[(size_t)BB * TT * VV + (size_t)brow * TT + (d + 1)] = (float)bc;
        if (brow == 0) {
          unsigned n0, n1;
          tf2x32(k0r, k1r, 0u, 0u, n0, n1);
          rng[((d + 1) & 1) * 2] = n0;
          rng[((d + 1) & 1) * 2 + 1] = n1;
        }
      }
      __syncthreads();
      int tkn = *tokp;
      xeT[tid * 64 + brow] = demb[(size_t)tkn * EE + tid];  // xe for next step
      float e0 = 0.f, e1 = 0.f, ssum = 0.f;
      {
        int c = tid;
        if (c < VV) { e0 = expf(lv[c] - m); ssum += e0; }
        c = tid + 256;
        if (c < VV) { e1 = expf(lv[c] - m); ssum += e1; }
      }
      for (int off = 32; off > 0; off >>= 1) ssum += __shfl_down(ssum, off, 64);
      if ((tid & 63) == 0) rf[tid >> 6] = ssum;
      __syncthreads();
      if (tid == 0) rf[4] = (rf[0] + rf[1]) + (rf[2] + rf[3]);
      __syncthreads();
      float S = rf[4];
      float* orow = out + ((size_t)brow * TT + (d + 1)) * VV;
      if (tid < VV) orow[tid] = e0 / S;
      if (tid + 256 < VV) orow[tid + 256] = e1 / S;
    }
    gbar(bar, ++gen, wg);
  }
}

extern "C" void kernel_launch(void* const* d_in, const int* in_sizes, int n_in,
                              void* d_out, int out_size, void* d_ws, size_t ws_size,
                              hipStream_t stream) {
  (void)in_sizes; (void)n_in; (void)out_size; (void)ws_size;
  const float* input = (const float*)d_in[0];
  const float* e_emb = (const float*)d_in[1];
  const float* eWih0 = (const float*)d_in[2];
  const float* eWhh0 = (const float*)d_in[3];
  const float* ebih0 = (const float*)d_in[4];
  const float* ebhh0 = (const float*)d_in[5];
  const float* eWih1 = (const float*)d_in[6];
  const float* eWhh1 = (const float*)d_in[7];
  const float* ebih1 = (const float*)d_in[8];
  const float* ebhh1 = (const float*)d_in[9];
  const float* d_emb = (const float*)d_in[10];
  const float* dWih0 = (const float*)d_in[11];
  const float* dWhh0 = (const float*)d_in[12];
  const float* dbih0 = (const float*)d_in[13];
  const float* dbhh0 = (const float*)d_in[14];
  const float* dWih1 = (const float*)d_in[15];
  const float* dWhh1 = (const float*)d_in[16];
  const float* dbih1 = (const float*)d_in[17];
  const float* dbhh1 = (const float*)d_in[18];
  const float* Wp1   = (const float*)d_in[19];
  const float* bp1   = (const float*)d_in[20];
  const float* Wp2   = (const float*)d_in[21];
  const float* bp2   = (const float*)d_in[22];
  float* out = (float*)d_out;

  // ws: xT (33.5MB) | h1 x2 | h2 x2 | xeT | rng | bar
  float* xT = (float*)d_ws;
  float* h1buf = xT + (size_t)TT * EE * 64;
  float* h2buf = h1buf + 2 * HH * BB;
  float* xeT = h2buf + 2 * HH * BB;
  unsigned* rng = (unsigned*)(xeT + EE * BB);
  unsigned* bar = rng + 16;

  k_init<<<64, 256, 0, stream>>>(out, h1buf, h2buf, xeT, rng, bar, d_emb);
  k_xgemm<<<TT, 256, 0, stream>>>(input, e_emb, xT);
  k_seq<<<256, 256, 23040 * sizeof(float), stream>>>(
      xT, h1buf, h2buf, xeT, rng, bar,
      eWih0, eWhh0, ebih0, ebhh0, eWih1, eWhh1, ebih1, ebhh1,
      d_emb, dWih0, dWhh0, dbih0, dbhh0, dWih1, dWhh1, dbih1, dbhh1,
      Wp1, bp1, Wp2, bp2, out);
}

// Round 3
// 118943.506 us; speedup vs baseline: 1.7343x; 1.7343x over previous
//
#include <hip/hip_runtime.h>
#include <math.h>

// Persistent weight-stationary seq2seq GRU + exact JAX threefry sampling.
// R3: R2 with the grid barrier fixed — fences ONCE per barrier (release wbl2 /
// acquire inv), RELAXED spin+signal atomics. R2's per-poll agent-scope
// acquire/release caused an L2 invalidate/writeback storm (~110us/barrier).
// All dot products keep R1's exact fmaf ordering -> tokens bit-identical.

#define BB 64
#define TT 512
#define VV 390
#define EE 256
#define HH 512
#define NTHR 256

static __device__ __forceinline__ void tf2x32(unsigned k0, unsigned k1,
                                              unsigned x0, unsigned x1,
                                              unsigned &o0, unsigned &o1) {
  unsigned ks2 = k0 ^ k1 ^ 0x1BD11BDAu;
  x0 += k0; x1 += k1;
#define TFR(r) x0 += x1; x1 = (x1 << (r)) | (x1 >> (32 - (r))); x1 ^= x0;
  TFR(13) TFR(15) TFR(26) TFR(6)
  x0 += k1; x1 += ks2 + 1u;
  TFR(17) TFR(29) TFR(16) TFR(24)
  x0 += ks2; x1 += k0 + 2u;
  TFR(13) TFR(15) TFR(26) TFR(6)
  x0 += k0; x1 += k1 + 3u;
  TFR(17) TFR(29) TFR(16) TFR(24)
  x0 += k1; x1 += ks2 + 4u;
  TFR(13) TFR(15) TFR(26) TFR(6)
  x0 += ks2; x1 += k0 + 5u;
#undef TFR
  o0 = x0; o1 = x1;
}

static __device__ __forceinline__ float sigm(float x) {
  return 1.0f / (1.0f + expf(-x));
}

// 3 dot products of rows w0/w1/w2 (contiguous, len K) against X laid out
// [k][64]. EXACT R1 fmaf ordering — do not touch (token bit-exactness).
template <int K>
static __device__ __forceinline__ void dot3_kb(const float* __restrict__ X, int b,
    const float* __restrict__ w0, const float* __restrict__ w1,
    const float* __restrict__ w2, float &r0, float &r1, float &r2) {
  const float4* q0 = (const float4*)w0;
  const float4* q1 = (const float4*)w1;
  const float4* q2 = (const float4*)w2;
  float s0 = 0.f, s1 = 0.f, s2 = 0.f;
#pragma unroll 4
  for (int k4 = 0; k4 < (K >> 2); ++k4) {
    float4 u0 = q0[k4], u1 = q1[k4], u2 = q2[k4];
    int kb = (k4 << 8) + b;
    float x0 = X[kb], x1 = X[kb + 64], x2 = X[kb + 128], x3 = X[kb + 192];
    s0 = fmaf(x0, u0.x, s0); s0 = fmaf(x1, u0.y, s0); s0 = fmaf(x2, u0.z, s0); s0 = fmaf(x3, u0.w, s0);
    s1 = fmaf(x0, u1.x, s1); s1 = fmaf(x1, u1.y, s1); s1 = fmaf(x2, u1.z, s1); s1 = fmaf(x3, u1.w, s1);
    s2 = fmaf(x0, u2.x, s2); s2 = fmaf(x1, u2.y, s2); s2 = fmaf(x2, u2.z, s2); s2 = fmaf(x3, u2.w, s2);
  }
  r0 = s0; r1 = s1; r2 = s2;
}

// Tree grid barrier: 16 groups x 16 WGs, monotone generation counters.
// bar[0]=root, bar[32+g*32]=group counters (128B apart).
// Fences ONCE per barrier; all spins/signals are RELAXED agent atomics
// (relaxed agent ops are served at the coherence point, so spins observe
// remote updates; no per-poll buffer_inv/buffer_wbl2).
static __device__ __forceinline__ void gbar(unsigned* bar, unsigned gen, int wg) {
  __syncthreads();
  if (threadIdx.x == 0) {
    unsigned tgt = gen * 16u;
    unsigned* grp = bar + 32 + (wg >> 4) * 32;
    __builtin_amdgcn_fence(__ATOMIC_RELEASE, "agent");  // one wbl2: data -> IC
    __hip_atomic_fetch_add(grp, 1u, __ATOMIC_RELAXED, __HIP_MEMORY_SCOPE_AGENT);
    if ((wg & 15) == 0) {
      while (__hip_atomic_load(grp, __ATOMIC_RELAXED, __HIP_MEMORY_SCOPE_AGENT) < tgt)
        __builtin_amdgcn_s_sleep(1);
      __builtin_amdgcn_fence(__ATOMIC_ACQUIRE, "agent");  // chain h-b through leader
      __hip_atomic_fetch_add(bar, 1u, __ATOMIC_RELEASE, __HIP_MEMORY_SCOPE_AGENT);
    }
    while (__hip_atomic_load(bar, __ATOMIC_RELAXED, __HIP_MEMORY_SCOPE_AGENT) < tgt)
      __builtin_amdgcn_s_sleep(1);
    __builtin_amdgcn_fence(__ATOMIC_ACQUIRE, "agent");  // one inv: re-read from IC
  }
  __syncthreads();
}

__global__ __launch_bounds__(256) void k_init(float* __restrict__ out,
    float* __restrict__ h1buf, float* __restrict__ h2buf,
    float* __restrict__ xeT, unsigned* __restrict__ rng,
    unsigned* __restrict__ bar, const float* __restrict__ demb) {
  int wg = blockIdx.x, tid = threadIdx.x;
  for (int i = wg * 256 + tid; i < HH * BB; i += 64 * 256) {
    h1buf[i] = 0.f;  // slot 0 only (slot 1 written before first read)
    h2buf[i] = 0.f;
  }
  for (int v = tid; v < VV; v += 256)
    out[(size_t)wg * TT * VV + v] = (v == 388) ? 1.0f : 0.0f;
  xeT[tid * 64 + wg] = demb[388 * EE + tid];  // xe for step 0 (token 388)
  if (tid == 0) {
    out[(size_t)BB * TT * VV + (size_t)wg * TT] = 388.0f;
    if (wg == 0) { rng[0] = 0u; rng[1] = 42u; rng[2] = 0u; rng[3] = 0u; }
  }
  if (wg == 0)
    for (int i = tid; i < 544; i += 256) bar[i] = 0u;
}

// x[t][e][b] = sum_v input[b][t][v] * emb[v][e]; one WG per t. (R1 verbatim)
__global__ __launch_bounds__(256) void k_xgemm(const float* __restrict__ input,
    const float* __restrict__ emb, float* __restrict__ xT) {
  int t = blockIdx.x, tid = threadIdx.x;
  int s = tid >> 6, b = tid & 63;
  __shared__ float lin[64 * 65];
  float4 acc[16];
#pragma unroll
  for (int i = 0; i < 16; ++i) acc[i] = make_float4(0.f, 0.f, 0.f, 0.f);
  for (int k0 = 0; k0 < VV; k0 += 64) {
    int kmax = min(64, VV - k0);
    __syncthreads();
#pragma unroll
    for (int r = 0; r < 16; ++r) {
      int idx = r * 256 + tid;
      int b2 = idx >> 6, kk = idx & 63;
      if (kk < kmax)
        lin[kk * 65 + b2] = input[((size_t)b2 * TT + t) * VV + k0 + kk];
    }
    __syncthreads();
    for (int kk = 0; kk < kmax; ++kk) {
      float xv = lin[kk * 65 + b];
      const float4* er = (const float4*)(emb + (size_t)(k0 + kk) * EE);
#pragma unroll
      for (int i = 0; i < 16; ++i) {
        float4 w = er[s + 4 * i];
        acc[i].x = fmaf(xv, w.x, acc[i].x);
        acc[i].y = fmaf(xv, w.y, acc[i].y);
        acc[i].z = fmaf(xv, w.z, acc[i].z);
        acc[i].w = fmaf(xv, w.w, acc[i].w);
      }
    }
  }
  float* dst0 = xT + (size_t)t * (EE * 64);
#pragma unroll
  for (int i = 0; i < 16; ++i) {
    int e = (s + 4 * i) * 4;
    float* d = dst0 + e * 64 + b;
    d[0] = acc[i].x; d[64] = acc[i].y; d[128] = acc[i].z; d[192] = acc[i].w;
  }
}

// LDS layout (floats):
//     0 encL0 u0 (3x768)   2304 encL0 u1   4608 encL1 u0 (3x1024)  7680 encL1 u1
// 10752 decL0 u0 (3x768)  13056 decL0 u1  15360 decL1 u0 (3x1024) 18432 decL1 u1
// 21504 scratch (1536): GRU partials / D5 head scratch
__global__ __launch_bounds__(256) void k_seq(
    const float* __restrict__ xT, float* __restrict__ h1buf, float* __restrict__ h2buf,
    float* __restrict__ xeT, unsigned* __restrict__ rng, unsigned* __restrict__ bar,
    const float* __restrict__ eWih0, const float* __restrict__ eWhh0,
    const float* __restrict__ ebih0, const float* __restrict__ ebhh0,
    const float* __restrict__ eWih1, const float* __restrict__ eWhh1,
    const float* __restrict__ ebih1, const float* __restrict__ ebhh1,
    const float* __restrict__ demb,
    const float* __restrict__ dWih0, const float* __restrict__ dWhh0,
    const float* __restrict__ dbih0, const float* __restrict__ dbhh0,
    const float* __restrict__ dWih1, const float* __restrict__ dWhh1,
    const float* __restrict__ dbih1, const float* __restrict__ dbhh1,
    const float* __restrict__ Wp1, const float* __restrict__ bp1,
    const float* __restrict__ Wp2, const float* __restrict__ bp2,
    float* __restrict__ out) {
  extern __shared__ float smem[];
  int wg = blockIdx.x, tid = threadIdx.x;
  int wv = tid >> 6, b = tid & 63;
  float* scr = smem + 21504;

  // ---- stage this WG's weight slices into LDS (j = 2*wg, 2*wg+1) ----
  for (int u = 0; u < 2; ++u) {
    int j = 2 * wg + u;
    for (int g = 0; g < 3; ++g) {
      float* d0 = smem + u * 2304 + g * 768;          // enc L0: [Wih(256)|Whh(512)]
      const float* s0 = eWih0 + (size_t)(g * 512 + j) * EE;
      for (int i = tid; i < EE; i += NTHR) d0[i] = s0[i];
      const float* s1 = eWhh0 + (size_t)(g * 512 + j) * HH;
      for (int i = tid; i < HH; i += NTHR) d0[EE + i] = s1[i];
      float* d1 = smem + 4608 + u * 3072 + g * 1024;  // enc L1: [Wih(512)|Whh(512)]
      const float* s2 = eWih1 + (size_t)(g * 512 + j) * HH;
      for (int i = tid; i < HH; i += NTHR) d1[i] = s2[i];
      const float* s3 = eWhh1 + (size_t)(g * 512 + j) * HH;
      for (int i = tid; i < HH; i += NTHR) d1[HH + i] = s3[i];
      float* d2 = smem + 10752 + u * 2304 + g * 768;  // dec L0
      const float* s4 = dWih0 + (size_t)(g * 512 + j) * EE;
      for (int i = tid; i < EE; i += NTHR) d2[i] = s4[i];
      const float* s5 = dWhh0 + (size_t)(g * 512 + j) * HH;
      for (int i = tid; i < HH; i += NTHR) d2[EE + i] = s5[i];
      float* d3 = smem + 15360 + u * 3072 + g * 1024; // dec L1
      const float* s6 = dWih1 + (size_t)(g * 512 + j) * HH;
      for (int i = tid; i < HH; i += NTHR) d3[i] = s6[i];
      const float* s7 = dWhh1 + (size_t)(g * 512 + j) * HH;
      for (int i = tid; i < HH; i += NTHR) d3[HH + i] = s7[i];
    }
  }
  __syncthreads();
  unsigned gen = 0;

  // ---- encoder: pipelined L0(step t) + L1(step t-1), 1 barrier/iter ----
  for (int t = 0; t <= TT; ++t) {
    bool isL1 = (wv >= 2);
    bool act = isL1 ? (t >= 1) : (t < TT);
    if (act) {
      int j = 2 * wg + (wv & 1);
      const float* h1r = h1buf + (t & 1) * (HH * BB);
      if (!isL1) {
        const float* wb = smem + (wv & 1) * 2304;
        float ax0, ax1, ax2, ah0, ah1, ah2;
        dot3_kb<EE>(xT + (size_t)t * (EE * 64), b, wb, wb + 768, wb + 1536, ax0, ax1, ax2);
        dot3_kb<HH>(h1r, b, wb + EE, wb + 768 + EE, wb + 1536 + EE, ah0, ah1, ah2);
        float r = sigm((ax0 + ebih0[j]) + (ah0 + ebhh0[j]));
        float z = sigm((ax1 + ebih0[512 + j]) + (ah1 + ebhh0[512 + j]));
        float n = tanhf((ax2 + ebih0[1024 + j]) + r * (ah2 + ebhh0[1024 + j]));
        float* h1w = h1buf + ((t + 1) & 1) * (HH * BB);
        h1w[j * 64 + b] = (1.0f - z) * n + z * h1r[j * 64 + b];
      } else {
        const float* wb = smem + 4608 + (wv & 1) * 3072;
        const float* h2r = h2buf + ((t + 1) & 1) * (HH * BB);
        float ax0, ax1, ax2, ah0, ah1, ah2;
        dot3_kb<HH>(h1r, b, wb, wb + 1024, wb + 2048, ax0, ax1, ax2);
        dot3_kb<HH>(h2r, b, wb + HH, wb + 1024 + HH, wb + 2048 + HH, ah0, ah1, ah2);
        float r = sigm((ax0 + ebih1[j]) + (ah0 + ebhh1[j]));
        float z = sigm((ax1 + ebih1[512 + j]) + (ah1 + ebhh1[512 + j]));
        float n = tanhf((ax2 + ebih1[1024 + j]) + r * (ah2 + ebhh1[1024 + j]));
        float* h2w = h2buf + (t & 1) * (HH * BB);
        h2w[j * 64 + b] = (1.0f - z) * n + z * h2r[j * 64 + b];
      }
    }
    gbar(bar, ++gen, wg);
  }

  // ---- decoder: 511 steps x (L0, L1, head+sample), 3 barriers/step ----
  for (int d = 0; d < TT - 1; ++d) {
    const float* h1r = h1buf + (d & 1) * (HH * BB);
    float* h1w = h1buf + ((d + 1) & 1) * (HH * BB);
    const float* h2r = h2buf + (d & 1) * (HH * BB);
    float* h2w = h2buf + ((d + 1) & 1) * (HH * BB);

    { // D1: dec layer0. wave = (unit, x/h-part); partials -> LDS -> combine.
      int unit = wv & 1, part = wv >> 1;
      const float* wb = smem + 10752 + unit * 2304;
      float a0, a1, a2;
      if (part == 0) dot3_kb<EE>(xeT, b, wb, wb + 768, wb + 1536, a0, a1, a2);
      else           dot3_kb<HH>(h1r, b, wb + EE, wb + 768 + EE, wb + 1536 + EE, a0, a1, a2);
      int pb = ((unit * 2 + part) * 3) * 64 + b;
      scr[pb] = a0; scr[pb + 64] = a1; scr[pb + 128] = a2;
      __syncthreads();
      if (tid < 128) {
        int u2 = tid >> 6, b2 = tid & 63, j2 = 2 * wg + u2;
        float ax0 = scr[(u2 * 6 + 0) * 64 + b2], ax1 = scr[(u2 * 6 + 1) * 64 + b2], ax2 = scr[(u2 * 6 + 2) * 64 + b2];
        float ah0 = scr[(u2 * 6 + 3) * 64 + b2], ah1 = scr[(u2 * 6 + 4) * 64 + b2], ah2 = scr[(u2 * 6 + 5) * 64 + b2];
        float r = sigm((ax0 + dbih0[j2]) + (ah0 + dbhh0[j2]));
        float z = sigm((ax1 + dbih0[512 + j2]) + (ah1 + dbhh0[512 + j2]));
        float n = tanhf((ax2 + dbih0[1024 + j2]) + r * (ah2 + dbhh0[1024 + j2]));
        h1w[j2 * 64 + b2] = (1.0f - z) * n + z * h1r[j2 * 64 + b2];
      }
    }
    gbar(bar, ++gen, wg);

    { // D2: dec layer1 (x-input = fresh h1).
      int unit = wv & 1, part = wv >> 1;
      const float* wb = smem + 15360 + unit * 3072;
      float a0, a1, a2;
      if (part == 0) dot3_kb<HH>(h1w, b, wb, wb + 1024, wb + 2048, a0, a1, a2);
      else           dot3_kb<HH>(h2r, b, wb + HH, wb + 1024 + HH, wb + 2048 + HH, a0, a1, a2);
      int pb = ((unit * 2 + part) * 3) * 64 + b;
      scr[pb] = a0; scr[pb + 64] = a1; scr[pb + 128] = a2;
      __syncthreads();
      if (tid < 128) {
        int u2 = tid >> 6, b2 = tid & 63, j2 = 2 * wg + u2;
        float ax0 = scr[(u2 * 6 + 0) * 64 + b2], ax1 = scr[(u2 * 6 + 1) * 64 + b2], ax2 = scr[(u2 * 6 + 2) * 64 + b2];
        float ah0 = scr[(u2 * 6 + 3) * 64 + b2], ah1 = scr[(u2 * 6 + 4) * 64 + b2], ah2 = scr[(u2 * 6 + 5) * 64 + b2];
        float r = sigm((ax0 + dbih1[j2]) + (ah0 + dbhh1[j2]));
        float z = sigm((ax1 + dbih1[512 + j2]) + (ah1 + dbhh1[512 + j2]));
        float n = tanhf((ax2 + dbih1[1024 + j2]) + r * (ah2 + dbhh1[1024 + j2]));
        h2w[j2 * 64 + b2] = (1.0f - z) * n + z * h2r[j2 * 64 + b2];
      }
    }
    gbar(bar, ++gen, wg);

    if (wg < 64) {  // D5: head + softmax + threefry-gumbel sample (R1 decC).
      float* lh = scr; float* lhid = scr + 512; float* lv = scr + 1024;
      float* rf = scr + 1414; int* ri = (int*)(scr + 1422); int* tokp = (int*)(scr + 1430);
      int brow = wg;
      lh[tid] = h2w[tid * 64 + brow];
      lh[tid + 256] = h2w[(tid + 256) * 64 + brow];
      __syncthreads();
      for (int c = tid; c < HH; c += 256) {
        const float4* w = (const float4*)(Wp1 + (size_t)c * HH);
        float a = 0.f;
#pragma unroll 4
        for (int k4 = 0; k4 < HH / 4; ++k4) {
          float4 q = w[k4];
          float4 hv = *(const float4*)&lh[k4 * 4];
          a = fmaf(hv.x, q.x, a); a = fmaf(hv.y, q.y, a);
          a = fmaf(hv.z, q.z, a); a = fmaf(hv.w, q.w, a);
        }
        a += bp1[c];
        lhid[c] = (a >= 0.f) ? a : 0.1f * a;
      }
      __syncthreads();
      for (int c = tid; c < VV; c += 256) {
        const float4* w = (const float4*)(Wp2 + (size_t)c * HH);
        float a = 0.f;
#pragma unroll 4
        for (int k4 = 0; k4 < HH / 4; ++k4) {
          float4 q = w[k4];
          float4 hv = *(const float4*)&lhid[k4 * 4];
          a = fmaf(hv.x, q.x, a); a = fmaf(hv.y, q.y, a);
          a = fmaf(hv.z, q.z, a); a = fmaf(hv.w, q.w, a);
        }
        lv[c] = a + bp2[c];
      }
      __syncthreads();
      float m = -INFINITY;
      for (int c = tid; c < VV; c += 256) m = fmaxf(m, lv[c]);
      for (int off = 32; off > 0; off >>= 1) m = fmaxf(m, __shfl_down(m, off, 64));
      if ((tid & 63) == 0) rf[tid >> 6] = m;
      __syncthreads();
      if (tid == 0) rf[4] = fmaxf(fmaxf(rf[0], rf[1]), fmaxf(rf[2], rf[3]));
      __syncthreads();
      m = rf[4];
      unsigned k0r = rng[(d & 1) * 2], k1r = rng[(d & 1) * 2 + 1];
      unsigned sk0, sk1;
      tf2x32(k0r, k1r, 0u, 1u, sk0, sk1);
      float by = -INFINITY; int bc = 0x7fffffff;
      for (int c = tid; c < VV; c += 256) {
        unsigned o0, o1;
        tf2x32(sk0, sk1, 0u, (unsigned)(brow * VV + c), o0, o1);
        unsigned bits = o0 ^ o1;
        float f = __uint_as_float(0x3f800000u | (bits >> 9)) - 1.0f;
        float u = (f > 0.f) ? f : 1.17549435e-38f;
        float g = (float)(-log(-log((double)u)));
        float y = lv[c] + g;
        if (y > by || (y == by && c < bc)) { by = y; bc = c; }
      }
      for (int off = 32; off > 0; off >>= 1) {
        float oy = __shfl_down(by, off, 64);
        int oc = __shfl_down(bc, off, 64);
        if (oy > by || (oy == by && oc < bc)) { by = oy; bc = oc; }
      }
      if ((tid & 63) == 0) { rf[tid >> 6] = by; ri[tid >> 6] = bc; }
      __syncthreads();
      if (tid == 0) {
        by = rf[0]; bc = ri[0];
        for (int w2 = 1; w2 < 4; ++w2)
          if (rf[w2] > by || (rf[w2] == by && ri[w2] < bc)) { by = rf[w2]; bc = ri[w2]; }
        *tokp = bc;
        out[(size_t)BB * TT * VV + (size_t)brow * TT + (d + 1)] = (float)bc;
        if (brow == 0) {
          unsigned n0, n1;
          tf2x32(k0r, k1r, 0u, 0u, n0, n1);
          rng[((d + 1) & 1) * 2] = n0;
          rng[((d + 1) & 1) * 2 + 1] = n1;
        }
      }
      __syncthreads();
      int tkn = *tokp;
      xeT[tid * 64 + brow] = demb[(size_t)tkn * EE + tid];  // xe for next step
      float e0 = 0.f, e1 = 0.f, ssum = 0.f;
      {
        int c = tid;
        if (c < VV) { e0 = expf(lv[c] - m); ssum += e0; }
        c = tid + 256;
        if (c < VV) { e1 = expf(lv[c] - m); ssum += e1; }
      }
      for (int off = 32; off > 0; off >>= 1) ssum += __shfl_down(ssum, off, 64);
      if ((tid & 63) == 0) rf[tid >> 6] = ssum;
      __syncthreads();
      if (tid == 0) rf[4] = (rf[0] + rf[1]) + (rf[2] + rf[3]);
      __syncthreads();
      float S = rf[4];
      float* orow = out + ((size_t)brow * TT + (d + 1)) * VV;
      if (tid < VV) orow[tid] = e0 / S;
      if (tid + 256 < VV) orow[tid + 256] = e1 / S;
    }
    gbar(bar, ++gen, wg);
  }
}

extern "C" void kernel_launch(void* const* d_in, const int* in_sizes, int n_in,
                              void* d_out, int out_size, void* d_ws, size_t ws_size,
                              hipStream_t stream) {
  (void)in_sizes; (void)n_in; (void)out_size; (void)ws_size;
  const float* input = (const float*)d_in[0];
  const float* e_emb = (const float*)d_in[1];
  const float* eWih0 = (const float*)d_in[2];
  const float* eWhh0 = (const float*)d_in[3];
  const float* ebih0 = (const float*)d_in[4];
  const float* ebhh0 = (const float*)d_in[5];
  const float* eWih1 = (const float*)d_in[6];
  const float* eWhh1 = (const float*)d_in[7];
  const float* ebih1 = (const float*)d_in[8];
  const float* ebhh1 = (const float*)d_in[9];
  const float* d_emb = (const float*)d_in[10];
  const float* dWih0 = (const float*)d_in[11];
  const float* dWhh0 = (const float*)d_in[12];
  const float* dbih0 = (const float*)d_in[13];
  const float* dbhh0 = (const float*)d_in[14];
  const float* dWih1 = (const float*)d_in[15];
  const float* dWhh1 = (const float*)d_in[16];
  const float* dbih1 = (const float*)d_in[17];
  const float* dbhh1 = (const float*)d_in[18];
  const float* Wp1   = (const float*)d_in[19];
  const float* bp1   = (const float*)d_in[20];
  const float* Wp2   = (const float*)d_in[21];
  const float* bp2   = (const float*)d_in[22];
  float* out = (float*)d_out;

  // ws: xT (33.5MB) | h1 x2 | h2 x2 | xeT | rng | bar
  float* xT = (float*)d_ws;
  float* h1buf = xT + (size_t)TT * EE * 64;
  float* h2buf = h1buf + 2 * HH * BB;
  float* xeT = h2buf + 2 * HH * BB;
  unsigned* rng = (unsigned*)(xeT + EE * BB);
  unsigned* bar = rng + 16;

  k_init<<<64, 256, 0, stream>>>(out, h1buf, h2buf, xeT, rng, bar, d_emb);
  k_xgemm<<<TT, 256, 0, stream>>>(input, e_emb, xT);
  k_seq<<<256, 256, 23040 * sizeof(float), stream>>>(
      xT, h1buf, h2buf, xeT, rng, bar,
      eWih0, eWhh0, ebih0, ebhh0, eWih1, eWhh1, ebih1, ebhh1,
      d_emb, dWih0, dWhh0, dbih0, dbhh0, dWih1, dWhh1, dbih1, dbhh1,
      Wp1, bp1, Wp2, bp2, out);
}